// Round 9
// baseline (382.629 us; speedup 1.0000x reference)
//
#include <hip/hip_runtime.h>

#define S_LEN 2048
#define E_DIM 1024
#define H_NUM 16

typedef __attribute__((ext_vector_type(8))) short s16x8;
typedef __attribute__((ext_vector_type(4))) float f32x4;
typedef __attribute__((ext_vector_type(4))) _Float16 h16x4;
typedef __attribute__((ext_vector_type(8))) _Float16 h16x8;

#define GA(p) ((__attribute__((address_space(1))) void*)(p))
#define LA(p) ((__attribute__((address_space(3))) void*)(p))

#define LOG2E 1.4426950408889634f
#define SCALE_Q (0.125f * LOG2E)
#define SHIFT 12.0f   // folded into QK accumulator init; cancels in p/l

union cvt16 { int4 v; s16x8 s8; short e[8]; };

__device__ __forceinline__ short f2bf(float f) {  // RNE
  union { float f; unsigned u; } v; v.f = f;
  unsigned r = v.u + 0x7FFFu + ((v.u >> 16) & 1u);
  return (short)(r >> 16);
}
__device__ __forceinline__ unsigned pkc(float lo, float hi) {  // 2xbf16, RNE
  unsigned r;
  asm("v_cvt_pk_bf16_f32 %0, %1, %2" : "=v"(r) : "v"(lo), "v"(hi));
  return r;
}

// ---------------------------------------------------------------------------
// Transpose + cast + scale: src fp32 (R x C) -> dst bf16 (C x R), batched.
// ---------------------------------------------------------------------------
__global__ void transpose_cast(const float* __restrict__ src, short* __restrict__ dst,
                               int R, int C, long sbs, long dbs, float scale) {
  __shared__ float tile[32][33];
  const float* s = src + (long)blockIdx.z * sbs;
  short* d = dst + (long)blockIdx.z * dbs;
  int c0 = blockIdx.x * 32, r0 = blockIdx.y * 32;
  #pragma unroll
  for (int i = threadIdx.y; i < 32; i += 8)
    tile[i][threadIdx.x] = s[(long)(r0 + i) * C + c0 + threadIdx.x];
  __syncthreads();
  #pragma unroll
  for (int i = threadIdx.y; i < 32; i += 8)
    d[(long)(c0 + i) * R + r0 + threadIdx.x] = f2bf(tile[threadIdx.x][i] * scale);
}

// ---------------------------------------------------------------------------
// Bias rearrange for swapped-QK flash layout. Lane (ln,quad) of q-row
// q = q0+w*32+i*16+ln needs, per kv tile, bias[q][kv*64 + nt*16 + quad*4 + r].
// Pack per (q, kv, quad) 16 f16 values:
//   biasR[q*2048 + kv*64 + quad*16 + c*8 + n2*4 + r] = bias[q][kv*64+(2c+n2)*16+quad*4+r]
// so flash does 2 x 16B loads per (i) per iter.
// ---------------------------------------------------------------------------
__global__ void bias_rearrange(const float* __restrict__ bias, _Float16* __restrict__ biasR) {
  long g = (long)blockIdx.x * 256 + threadIdx.x;   // 16B-chunk id, 524288 total
  int q    = (int)(g >> 8);
  int kv   = ((int)(g >> 3)) & 31;
  int quad = ((int)(g >> 1)) & 3;
  int c    = (int)g & 1;
  const float* src = bias + (long)q * 2048 + kv * 64 + c * 32 + quad * 4;
  f32x4 lo = *(const f32x4*)(src);        // n2 = 0 : t = base + r
  f32x4 hi = *(const f32x4*)(src + 16);   // n2 = 1 : t = base + 16 + r
  h16x8 hv;
  #pragma unroll
  for (int e = 0; e < 4; ++e) { hv[e] = (_Float16)lo[e]; hv[4 + e] = (_Float16)hi[e]; }
  *(h16x8*)(biasR + g * 8) = hv;
}

// ---------------------------------------------------------------------------
// QKV projection GEMM, fp32-A direct DMA staging.
// A: fp32 (8192x1024) per segment, Bt: bf16 (3072x1024).
// Segs 0/1 -> qk (8192x2048); seg 2 -> VT [(b*16+h)*64+d][pi(t)] where pi
// permutes t within each 64-block (bit shuffle (kk,n2,quad,r)->(kk,quad,n2,r))
// so flash's in-lane P packing lines up with V's PV k-slots.
// A-fragment bf16 conversion via v_cvt_pk_bf16_f32 (4 instrs/frag, RNE).
// ---------------------------------------------------------------------------
__global__ __launch_bounds__(256, 3) void proj_gemm(
    const float* __restrict__ Aq, const float* __restrict__ Ak, const float* __restrict__ Av,
    const short* __restrict__ Bt,
    const float* __restrict__ bq, const float* __restrict__ bk, const float* __restrict__ bv,
    short* __restrict__ qkOut, short* __restrict__ VT) {
  __shared__ float Asub[128 * 64];   // 32 KB, fp32, swizzled 16B chunks
  __shared__ short Bsub[128 * 64];   // 16 KB, bf16, swizzled 16B chunks
  const int tid = threadIdx.x;
  const int w = tid >> 6, lane = tid & 63, ln = lane & 15, quad = lane >> 4;
  const int row0 = blockIdx.x * 128, n0 = blockIdx.y * 128;
  const int seg = n0 >> 10;
  const float* A = (seg == 0) ? Aq : ((seg == 1) ? Ak : Av);
  const float* bptr = (seg == 0) ? bq : ((seg == 1) ? bk : bv);
  const float bscale = (seg == 0) ? SCALE_Q : 1.0f;
  const int nloc = n0 & 1023;
  const int wm = (w & 1) * 64, wn = (w >> 1) * 64;

  f32x4 acc[4][4];
  #pragma unroll
  for (int i = 0; i < 4; ++i)
    #pragma unroll
    for (int j = 0; j < 4; ++j) acc[i][j] = (f32x4){0.f, 0.f, 0.f, 0.f};

  for (int kt = 0; kt < 16; ++kt) {
    const int k0 = kt * 64;
    #pragma unroll
    for (int j = 0; j < 4; ++j) {
      int ci = (w * 4 + j) * 64 + lane;
      int r = ci >> 3, s = ci & 7, g = s ^ (r & 7);
      const short* gb = Bt + (long)(n0 + r) * 1024 + k0 + g * 8;
      __builtin_amdgcn_global_load_lds(GA(gb), LA(&Bsub[ci * 8]), 16, 0, 0);
    }
    #pragma unroll
    for (int it = 0; it < 8; ++it) {
      int ci = it * 256 + tid;
      int r = ci >> 4, s = ci & 15, g = (s & 8) | ((s & 7) ^ (r & 7));
      const float* ga = A + (long)(row0 + r) * 1024 + k0 + g * 4;
      __builtin_amdgcn_global_load_lds(GA(ga), LA(&Asub[ci * 4]), 16, 0, 0);
    }
    __syncthreads();
    #pragma unroll
    for (int kk = 0; kk < 2; ++kk) {
      s16x8 af[4], bfr[4];
      #pragma unroll
      for (int i = 0; i < 4; ++i) {
        int ra = wm + i * 16 + ln;
        int c0 = kk * 8 + quad * 2;
        int s0 = (c0 & 8) | ((c0 & 7) ^ (ra & 7));
        int c1 = c0 + 1;
        int s1 = (c1 & 8) | ((c1 & 7) ^ (ra & 7));
        f32x4 lo = *(const f32x4*)&Asub[ra * 64 + s0 * 4];
        f32x4 hi = *(const f32x4*)&Asub[ra * 64 + s1 * 4];
        union { unsigned u[4]; s16x8 v; } t;
        t.u[0] = pkc(lo[0], lo[1]);
        t.u[1] = pkc(lo[2], lo[3]);
        t.u[2] = pkc(hi[0], hi[1]);
        t.u[3] = pkc(hi[2], hi[3]);
        af[i] = t.v;
      }
      #pragma unroll
      for (int j = 0; j < 4; ++j) {
        int rb = wn + j * 16 + ln;
        int slot = (kk * 4 + quad) ^ (rb & 7);
        bfr[j] = *(const s16x8*)&Bsub[rb * 64 + slot * 8];
      }
      #pragma unroll
      for (int i = 0; i < 4; ++i)
        #pragma unroll
        for (int j = 0; j < 4; ++j)
          acc[i][j] = __builtin_amdgcn_mfma_f32_16x16x32_bf16(af[i], bfr[j], acc[i][j], 0, 0, 0);
    }
    __syncthreads();
  }
  if (seg < 2) {
    #pragma unroll
    for (int j = 0; j < 4; ++j) {
      float bvj = bptr[nloc + wn + j * 16 + ln] * bscale;
      int n = n0 + wn + j * 16 + ln;
      #pragma unroll
      for (int i = 0; i < 4; ++i)
        #pragma unroll
        for (int r = 0; r < 4; ++r) {
          int row = row0 + wm + i * 16 + quad * 4 + r;
          qkOut[(long)row * 2048 + n] = f2bf(acc[i][j][r] + bvj);
        }
    }
  } else {
    #pragma unroll
    for (int j = 0; j < 4; ++j) {
      int nl = nloc + wn + j * 16 + ln;
      int hh = nl >> 6, d = nl & 63;
      float bvj = bptr[nl];
      #pragma unroll
      for (int i = 0; i < 4; ++i) {
        int row = row0 + wm + i * 16 + quad * 4;
        int b = row >> 11, t = row & 2047;
        int u = t & 63;   // pi: (kk,n2,quad,r) -> (kk,quad,n2,r); r bits kept
        int pt = (t & ~63) | (u & 0x23) | ((u & 0x10) >> 2) | ((u & 0x0C) << 1);
        short4 sv;
        sv.x = f2bf(acc[i][j][0] + bvj);
        sv.y = f2bf(acc[i][j][1] + bvj);
        sv.z = f2bf(acc[i][j][2] + bvj);
        sv.w = f2bf(acc[i][j][3] + bvj);
        *(short4*)&VT[((long)(b * 16 + hh) * 64 + d) * 2048 + pt] = sv;
      }
    }
  }
}

// ---------------------------------------------------------------------------
// Flash attention, swapped-QK in-register softmax, NO cross-lane traffic.
// mfma(K,Q): lane (ln,quad) holds S[q=i*16+ln][t=nt*16+quad*4+r].
// V stored t-permuted (pi) so the PV A-fragment is built by in-lane packing.
// Bias pipelining WITHOUT extra registers (R8 lesson: bldn's +16 VGPR cost a
// residency level, 3->2 blocks/CU): sa-init consumes bld (bias kv), then the
// SAME bld registers are refilled with kv+1's bias — live ranges don't
// overlap, so no copy and no extra allocation. Loads get QK+softmax+PV
// (~2000+ cyc) + the barrier to land before next use. sched_barrier pins
// them above the QK MFMA cluster.
// LDS = K/V double-buffer only (32KB); Ks reused as l-reduce scratch at end.
// ---------------------------------------------------------------------------
__global__ __launch_bounds__(256, 3) void flash_attn(
    const short* __restrict__ qk, const short* __restrict__ VT,
    const _Float16* __restrict__ biasR, short* __restrict__ concat) {
  __shared__ short Ks[2][4096];   // (t, d) xor-swizzled 16B chunks
  __shared__ short Vs[2][4096];   // (d, t-permuted) xor-swizzled 16B chunks
  const int tid = threadIdx.x;
  const int w = tid >> 6, lane = tid & 63, ln = lane & 15, quad = lane >> 4;
  const int q0 = blockIdx.x * 128;
  const int h = blockIdx.y, bb = blockIdx.z;

  // Q fragments (pre-scaled by log2e/8 at prep); B-frag rows q=i*16+ln
  s16x8 qf[2][2];
  const short* qbase = qk + (long)(bb * 2048 + q0 + w * 32) * 2048 + h * 64;
  #pragma unroll
  for (int i = 0; i < 2; ++i)
    #pragma unroll
    for (int kk = 0; kk < 2; ++kk) {
      cvt16 u; u.v = *(const int4*)(qbase + (long)(i * 16 + ln) * 2048 + kk * 32 + quad * 8);
      qf[i][kk] = u.s8;
    }

  f32x4 o[2][4];
  float lsum[2] = {0.f, 0.f};
  #pragma unroll
  for (int i = 0; i < 2; ++i)
    #pragma unroll
    for (int nt = 0; nt < 4; ++nt) o[i][nt] = (f32x4){0.f, 0.f, 0.f, 0.f};

  const short* kbase = qk + (long)bb * 2048 * 2048 + 1024 + h * 64;
  const short* vbase = VT + (long)(bb * 16 + h) * 64 * 2048;
  // bias: per (i,c) 16B at q*2048 + quad*16 + kv*64 + c*8
  const _Float16* bbase = biasR + (long)(q0 + w * 32 + ln) * 2048 + quad * 16;

  // stage kv=0 into buffer 0; bias for kv=0 loaded alongside
  #pragma unroll
  for (int j = 0; j < 2; ++j) {
    int ci = (w * 2 + j) * 64 + lane;
    int r = ci >> 3, cs = (ci & 7) ^ (r & 7);
    __builtin_amdgcn_global_load_lds(GA(kbase + (long)r * 2048 + cs * 8), LA(&Ks[0][(w * 2 + j) * 512]), 16, 0, 0);
    __builtin_amdgcn_global_load_lds(GA(vbase + (long)r * 2048 + cs * 8), LA(&Vs[0][(w * 2 + j) * 512]), 16, 0, 0);
  }
  h16x8 bld[2][2];
  #pragma unroll
  for (int i = 0; i < 2; ++i)
    #pragma unroll
    for (int c = 0; c < 2; ++c)
      bld[i][c] = *(const h16x8*)(bbase + (long)i * 16 * 2048 + c * 8);

  for (int kv = 0; kv < 32; ++kv) {
    const int t0 = kv * 64, b = kv & 1;
    __syncthreads();  // own DMA+bias drained pre-barrier -> buf b ready

    if (kv < 31) {  // prefetch kv+1 K/V into other buffer
      const short* kb = kbase + (long)(t0 + 64) * 2048;
      const short* vb = vbase + (t0 + 64);
      #pragma unroll
      for (int j = 0; j < 2; ++j) {
        int ci = (w * 2 + j) * 64 + lane;
        int r = ci >> 3, cs = (ci & 7) ^ (r & 7);
        __builtin_amdgcn_global_load_lds(GA(kb + (long)r * 2048 + cs * 8), LA(&Ks[b ^ 1][(w * 2 + j) * 512]), 16, 0, 0);
        __builtin_amdgcn_global_load_lds(GA(vb + (long)r * 2048 + cs * 8), LA(&Vs[b ^ 1][(w * 2 + j) * 512]), 16, 0, 0);
      }
    }

    // accumulator init carries bias (regs loaded LAST iter, already landed):
    // sa = bias*log2e - SHIFT; sa[i][nt] lane holds S[q=i*16+ln][t=t0+nt*16+quad*4+r]
    f32x4 sa[2][4];
    #pragma unroll
    for (int i = 0; i < 2; ++i)
      #pragma unroll
      for (int nt = 0; nt < 4; ++nt)
        #pragma unroll
        for (int r = 0; r < 4; ++r)
          sa[i][nt][r] = fmaf((float)bld[i][nt >> 1][(nt & 1) * 4 + r], LOG2E, -SHIFT);

    // bld is now dead: refill the SAME registers with kv+1's bias (no copy,
    // no extra liveness); they have the rest of this iter + barrier to land.
    if (kv < 31) {
      #pragma unroll
      for (int i = 0; i < 2; ++i)
        #pragma unroll
        for (int c = 0; c < 2; ++c)
          bld[i][c] = *(const h16x8*)(bbase + (long)i * 16 * 2048 + (kv + 1) * 64 + c * 8);
    }
    __builtin_amdgcn_sched_barrier(0);

    #pragma unroll
    for (int kk = 0; kk < 2; ++kk) {
      s16x8 bfr[4];
      #pragma unroll
      for (int nt = 0; nt < 4; ++nt)
        bfr[nt] = *(const s16x8*)&Ks[b][((nt * 16 + ln) << 6) + (((kk * 4 + quad) ^ (ln & 7)) << 3)];
      __builtin_amdgcn_s_setprio(1);
      #pragma unroll
      for (int i = 0; i < 2; ++i)
        #pragma unroll
        for (int nt = 0; nt < 4; ++nt)
          sa[i][nt] = __builtin_amdgcn_mfma_f32_16x16x32_bf16(bfr[nt], qf[i][kk], sa[i][nt], 0, 0, 0);
      __builtin_amdgcn_s_setprio(0);
    }

    // p = 2^sa; row-sum into lsum; pack in-lane into PV A-frags (RNE)
    s16x8 pa[2][2];
    #pragma unroll
    for (int i = 0; i < 2; ++i) {
      #pragma unroll
      for (int nt = 0; nt < 4; ++nt)
        #pragma unroll
        for (int r = 0; r < 4; ++r)
          sa[i][nt][r] = __builtin_amdgcn_exp2f(sa[i][nt][r]);
      f32x4 vs = (sa[i][0] + sa[i][1]) + (sa[i][2] + sa[i][3]);
      lsum[i] += (vs[0] + vs[1]) + (vs[2] + vs[3]);
      #pragma unroll
      for (int kk = 0; kk < 2; ++kk) {
        union { unsigned u[4]; s16x8 v; } pw;
        pw.u[0] = pkc(sa[i][2 * kk][0], sa[i][2 * kk][1]);
        pw.u[1] = pkc(sa[i][2 * kk][2], sa[i][2 * kk][3]);
        pw.u[2] = pkc(sa[i][2 * kk + 1][0], sa[i][2 * kk + 1][1]);
        pw.u[3] = pkc(sa[i][2 * kk + 1][2], sa[i][2 * kk + 1][3]);
        pa[i][kk] = pw.v;
      }
    }

    // O += P.V   (V t-permuted to match pa's k-slot order)
    #pragma unroll
    for (int kk = 0; kk < 2; ++kk) {
      s16x8 vbf[4];
      #pragma unroll
      for (int nt = 0; nt < 4; ++nt)
        vbf[nt] = *(const s16x8*)&Vs[b][((nt * 16 + ln) << 6) + (((kk * 4 + quad) ^ (ln & 7)) << 3)];
      __builtin_amdgcn_s_setprio(1);
      #pragma unroll
      for (int i = 0; i < 2; ++i)
        #pragma unroll
        for (int nt = 0; nt < 4; ++nt)
          o[i][nt] = __builtin_amdgcn_mfma_f32_16x16x32_bf16(pa[i][kk], vbf[nt], o[i][nt], 0, 0, 0);
      __builtin_amdgcn_s_setprio(0);
    }
  }

  // epilogue: cross-quad l-reduction via LDS (Ks dead; reuse as scratch),
  // then O / l -> concat (rows q = i*16 + quad*4 + r)
  __syncthreads();   // all waves past their last Ks read
  float* lred = (float*)&Ks[0][0];   // 4 waves x 128 floats = 2KB
  #pragma unroll
  for (int i = 0; i < 2; ++i)
    lred[w * 128 + i * 64 + ln * 4 + quad] = lsum[i];
  __syncthreads();
  #pragma unroll
  for (int i = 0; i < 2; ++i) {
    float inv[4];
    #pragma unroll
    for (int r = 0; r < 4; ++r) {
      f32x4 lv = *(const f32x4*)&lred[w * 128 + i * 64 + (quad * 4 + r) * 4];
      inv[r] = __builtin_amdgcn_rcpf((lv[0] + lv[1]) + (lv[2] + lv[3]));
    }
    long rowb = (long)bb * 2048 + q0 + w * 32 + i * 16 + quad * 4;
    #pragma unroll
    for (int nt = 0; nt < 4; ++nt)
      #pragma unroll
      for (int r = 0; r < 4; ++r)
        concat[(rowb + r) * 1024 + h * 64 + nt * 16 + ln] = f2bf(o[i][nt][r] * inv[r]);
  }
}

// ---------------------------------------------------------------------------
// Output GEMM: out[row, n] = sum_k concat[row, k] * WoT[n, k] + bo[n], fp32 out
// ---------------------------------------------------------------------------
__global__ __launch_bounds__(256, 3) void out_gemm(
    const short* __restrict__ A, const short* __restrict__ Bt,
    const float* __restrict__ bo, float* __restrict__ Cout) {
  __shared__ short Asub[128 * 64];
  __shared__ short Bsub[128 * 64];
  const int tid = threadIdx.x;
  const int w = tid >> 6, lane = tid & 63, ln = lane & 15, quad = lane >> 4;
  const int row0 = blockIdx.x * 128, n0 = blockIdx.y * 128;
  const int wm = (w & 1) * 64, wn = (w >> 1) * 64;

  f32x4 acc[4][4];
  #pragma unroll
  for (int i = 0; i < 4; ++i)
    #pragma unroll
    for (int j = 0; j < 4; ++j) acc[i][j] = (f32x4){0.f, 0.f, 0.f, 0.f};

  for (int kt = 0; kt < 16; ++kt) {
    const int k0 = kt * 64;
    #pragma unroll
    for (int j = 0; j < 4; ++j) {
      int ci = (w * 4 + j) * 64 + lane;
      int r = ci >> 3, s = ci & 7, g = s ^ (r & 7);
      const short* ga = A + (long)(row0 + r) * 1024 + k0 + g * 8;
      __builtin_amdgcn_global_load_lds(GA(ga), LA(&Asub[ci * 8]), 16, 0, 0);
      const short* gb = Bt + (long)(n0 + r) * 1024 + k0 + g * 8;
      __builtin_amdgcn_global_load_lds(GA(gb), LA(&Bsub[ci * 8]), 16, 0, 0);
    }
    __syncthreads();
    #pragma unroll
    for (int kk = 0; kk < 2; ++kk) {
      s16x8 af[4], bfr[4];
      #pragma unroll
      for (int i = 0; i < 4; ++i) {
        int ra = wm + i * 16 + ln;
        int slot = (kk * 4 + quad) ^ (ra & 7);
        af[i] = *(const s16x8*)&Asub[ra * 64 + slot * 8];
      }
      #pragma unroll
      for (int j = 0; j < 4; ++j) {
        int rb = wn + j * 16 + ln;
        int slot = (kk * 4 + quad) ^ (rb & 7);
        bfr[j] = *(const s16x8*)&Bsub[rb * 64 + slot * 8];
      }
      #pragma unroll
      for (int i = 0; i < 4; ++i)
        #pragma unroll
        for (int j = 0; j < 4; ++j)
          acc[i][j] = __builtin_amdgcn_mfma_f32_16x16x32_bf16(af[i], bfr[j], acc[i][j], 0, 0, 0);
    }
    __syncthreads();
  }
  #pragma unroll
  for (int j = 0; j < 4; ++j) {
    int n = n0 + wn + j * 16 + ln;
    float bvj = bo[n];
    #pragma unroll
    for (int i = 0; i < 4; ++i)
      #pragma unroll
      for (int r = 0; r < 4; ++r) {
        int row = row0 + wm + i * 16 + quad * 4 + r;
        Cout[(long)row * 1024 + n] = acc[i][j][r] + bvj;
      }
  }
}

// ---------------------------------------------------------------------------
// ws layout (72 MB total, proven budget):
//   [ 0, 8M)  WqkvT bf16 (6MB) -> overwritten by biasR fp16 (8MB) after proj
//   [ 8,40M)  qk bf16 (8192 x 2048)
//   [40,56M)  VT bf16 [(b,h,d) x pi(t)] -> WoT bf16 (2MB) overwrites after flash
//   [56,72M)  concat bf16 (8192 x 1024)
// ---------------------------------------------------------------------------
extern "C" void kernel_launch(void* const* d_in, const int* in_sizes, int n_in,
                              void* d_out, int out_size, void* d_ws, size_t ws_size,
                              hipStream_t stream) {
  const float* query = (const float*)d_in[0];
  const float* key_  = (const float*)d_in[1];
  const float* value = (const float*)d_in[2];
  const float* abias = (const float*)d_in[3];
  const float* Wq = (const float*)d_in[4];
  const float* bq = (const float*)d_in[5];
  const float* Wk = (const float*)d_in[6];
  const float* bk = (const float*)d_in[7];
  const float* Wv = (const float*)d_in[8];
  const float* bv = (const float*)d_in[9];
  const float* Wo = (const float*)d_in[10];
  const float* bo = (const float*)d_in[11];
  float* out = (float*)d_out;

  char* ws = (char*)d_ws;
  short*    WqkvT  = (short*)(ws);
  _Float16* biasR  = (_Float16*)(ws);
  short*    qk     = (short*)(ws + 8388608);
  short*    VT     = (short*)(ws + 41943040);
  short*    WoT    = (short*)(ws + 41943040);
  short*    concat = (short*)(ws + 58720256);

  dim3 tb(32, 8);
  transpose_cast<<<dim3(2, 32, 16), tb, 0, stream>>>(Wq, WqkvT,           1024, 64, 65536L, 65536L, SCALE_Q);
  transpose_cast<<<dim3(2, 32, 16), tb, 0, stream>>>(Wk, WqkvT + 1048576, 1024, 64, 65536L, 65536L, 1.0f);
  transpose_cast<<<dim3(2, 32, 16), tb, 0, stream>>>(Wv, WqkvT + 2097152, 1024, 64, 65536L, 65536L, 1.0f);
  proj_gemm<<<dim3(64, 24), 256, 0, stream>>>(query, key_, value, WqkvT, bq, bk, bv, qk, VT);
  bias_rearrange<<<dim3(2048), 256, 0, stream>>>(abias, biasR);
  flash_attn<<<dim3(16, 16, 4), 256, 0, stream>>>(qk, VT, biasR, concat);
  transpose_cast<<<dim3(32, 32, 1), tb, 0, stream>>>(Wo, WoT, 1024, 1024, 0L, 0L, 1.0f);
  out_gemm<<<dim3(64, 8), 256, 0, stream>>>(concat, WoT, bo, out);
}

// Round 10
// 369.315 us; speedup vs baseline: 1.0361x; 1.0361x over previous
//
#include <hip/hip_runtime.h>

#define S_LEN 2048
#define E_DIM 1024
#define H_NUM 16

typedef __attribute__((ext_vector_type(8))) short s16x8;
typedef __attribute__((ext_vector_type(4))) float f32x4;
typedef __attribute__((ext_vector_type(4))) _Float16 h16x4;
typedef __attribute__((ext_vector_type(8))) _Float16 h16x8;

#define GA(p) ((__attribute__((address_space(1))) void*)(p))
#define LA(p) ((__attribute__((address_space(3))) void*)(p))

#define LOG2E 1.4426950408889634f
#define SCALE_Q (0.125f * LOG2E)
#define SHIFT 12.0f   // folded into QK accumulator init; cancels in p/l

union cvt16 { int4 v; s16x8 s8; short e[8]; };

__device__ __forceinline__ short f2bf(float f) {  // RNE
  union { float f; unsigned u; } v; v.f = f;
  unsigned r = v.u + 0x7FFFu + ((v.u >> 16) & 1u);
  return (short)(r >> 16);
}
__device__ __forceinline__ unsigned pkc(float lo, float hi) {  // 2xbf16, RNE
  unsigned r;
  asm("v_cvt_pk_bf16_f32 %0, %1, %2" : "=v"(r) : "v"(lo), "v"(hi));
  return r;
}

// ---------------------------------------------------------------------------
// Transpose + cast + scale: src fp32 (R x C) -> dst bf16 (C x R), batched.
// ---------------------------------------------------------------------------
__global__ void transpose_cast(const float* __restrict__ src, short* __restrict__ dst,
                               int R, int C, long sbs, long dbs, float scale) {
  __shared__ float tile[32][33];
  const float* s = src + (long)blockIdx.z * sbs;
  short* d = dst + (long)blockIdx.z * dbs;
  int c0 = blockIdx.x * 32, r0 = blockIdx.y * 32;
  #pragma unroll
  for (int i = threadIdx.y; i < 32; i += 8)
    tile[i][threadIdx.x] = s[(long)(r0 + i) * C + c0 + threadIdx.x];
  __syncthreads();
  #pragma unroll
  for (int i = threadIdx.y; i < 32; i += 8)
    d[(long)(c0 + i) * R + r0 + threadIdx.x] = f2bf(tile[threadIdx.x][i] * scale);
}

// ---------------------------------------------------------------------------
// Bias rearrange for swapped-QK flash layout. Lane (ln,quad) of q-row
// q = q0+w*32+i*16+ln needs, per kv tile, bias[q][kv*64 + nt*16 + quad*4 + r].
// Pack per (q, kv, quad) 16 f16 values:
//   biasR[q*2048 + kv*64 + quad*16 + c*8 + n2*4 + r] = bias[q][kv*64+(2c+n2)*16+quad*4+r]
// so flash does 2 x 16B loads per (i) per iter.
// ---------------------------------------------------------------------------
__global__ void bias_rearrange(const float* __restrict__ bias, _Float16* __restrict__ biasR) {
  long g = (long)blockIdx.x * 256 + threadIdx.x;   // 16B-chunk id, 524288 total
  int q    = (int)(g >> 8);
  int kv   = ((int)(g >> 3)) & 31;
  int quad = ((int)(g >> 1)) & 3;
  int c    = (int)g & 1;
  const float* src = bias + (long)q * 2048 + kv * 64 + c * 32 + quad * 4;
  f32x4 lo = *(const f32x4*)(src);        // n2 = 0 : t = base + r
  f32x4 hi = *(const f32x4*)(src + 16);   // n2 = 1 : t = base + 16 + r
  h16x8 hv;
  #pragma unroll
  for (int e = 0; e < 4; ++e) { hv[e] = (_Float16)lo[e]; hv[4 + e] = (_Float16)hi[e]; }
  *(h16x8*)(biasR + g * 8) = hv;
}

// ---------------------------------------------------------------------------
// QKV projection GEMM, fp32-A direct DMA staging.
// A: fp32 (8192x1024) per segment, Bt: bf16 (3072x1024).
// Segs 0/1 -> qk (8192x2048); seg 2 -> VT [(b*16+h)*64+d][pi(t)] where pi
// permutes t within each 64-block (bit shuffle (kk,n2,quad,r)->(kk,quad,n2,r))
// so flash's in-lane P packing lines up with V's PV k-slots.
// A-fragment bf16 conversion via v_cvt_pk_bf16_f32 (4 instrs/frag, RNE).
// ---------------------------------------------------------------------------
__global__ __launch_bounds__(256, 3) void proj_gemm(
    const float* __restrict__ Aq, const float* __restrict__ Ak, const float* __restrict__ Av,
    const short* __restrict__ Bt,
    const float* __restrict__ bq, const float* __restrict__ bk, const float* __restrict__ bv,
    short* __restrict__ qkOut, short* __restrict__ VT) {
  __shared__ float Asub[128 * 64];   // 32 KB, fp32, swizzled 16B chunks
  __shared__ short Bsub[128 * 64];   // 16 KB, bf16, swizzled 16B chunks
  const int tid = threadIdx.x;
  const int w = tid >> 6, lane = tid & 63, ln = lane & 15, quad = lane >> 4;
  const int row0 = blockIdx.x * 128, n0 = blockIdx.y * 128;
  const int seg = n0 >> 10;
  const float* A = (seg == 0) ? Aq : ((seg == 1) ? Ak : Av);
  const float* bptr = (seg == 0) ? bq : ((seg == 1) ? bk : bv);
  const float bscale = (seg == 0) ? SCALE_Q : 1.0f;
  const int nloc = n0 & 1023;
  const int wm = (w & 1) * 64, wn = (w >> 1) * 64;

  f32x4 acc[4][4];
  #pragma unroll
  for (int i = 0; i < 4; ++i)
    #pragma unroll
    for (int j = 0; j < 4; ++j) acc[i][j] = (f32x4){0.f, 0.f, 0.f, 0.f};

  for (int kt = 0; kt < 16; ++kt) {
    const int k0 = kt * 64;
    #pragma unroll
    for (int j = 0; j < 4; ++j) {
      int ci = (w * 4 + j) * 64 + lane;
      int r = ci >> 3, s = ci & 7, g = s ^ (r & 7);
      const short* gb = Bt + (long)(n0 + r) * 1024 + k0 + g * 8;
      __builtin_amdgcn_global_load_lds(GA(gb), LA(&Bsub[ci * 8]), 16, 0, 0);
    }
    #pragma unroll
    for (int it = 0; it < 8; ++it) {
      int ci = it * 256 + tid;
      int r = ci >> 4, s = ci & 15, g = (s & 8) | ((s & 7) ^ (r & 7));
      const float* ga = A + (long)(row0 + r) * 1024 + k0 + g * 4;
      __builtin_amdgcn_global_load_lds(GA(ga), LA(&Asub[ci * 4]), 16, 0, 0);
    }
    __syncthreads();
    #pragma unroll
    for (int kk = 0; kk < 2; ++kk) {
      s16x8 af[4], bfr[4];
      #pragma unroll
      for (int i = 0; i < 4; ++i) {
        int ra = wm + i * 16 + ln;
        int c0 = kk * 8 + quad * 2;
        int s0 = (c0 & 8) | ((c0 & 7) ^ (ra & 7));
        int c1 = c0 + 1;
        int s1 = (c1 & 8) | ((c1 & 7) ^ (ra & 7));
        f32x4 lo = *(const f32x4*)&Asub[ra * 64 + s0 * 4];
        f32x4 hi = *(const f32x4*)&Asub[ra * 64 + s1 * 4];
        union { unsigned u[4]; s16x8 v; } t;
        t.u[0] = pkc(lo[0], lo[1]);
        t.u[1] = pkc(lo[2], lo[3]);
        t.u[2] = pkc(hi[0], hi[1]);
        t.u[3] = pkc(hi[2], hi[3]);
        af[i] = t.v;
      }
      #pragma unroll
      for (int j = 0; j < 4; ++j) {
        int rb = wn + j * 16 + ln;
        int slot = (kk * 4 + quad) ^ (rb & 7);
        bfr[j] = *(const s16x8*)&Bsub[rb * 64 + slot * 8];
      }
      #pragma unroll
      for (int i = 0; i < 4; ++i)
        #pragma unroll
        for (int j = 0; j < 4; ++j)
          acc[i][j] = __builtin_amdgcn_mfma_f32_16x16x32_bf16(af[i], bfr[j], acc[i][j], 0, 0, 0);
    }
    __syncthreads();
  }
  if (seg < 2) {
    #pragma unroll
    for (int j = 0; j < 4; ++j) {
      float bvj = bptr[nloc + wn + j * 16 + ln] * bscale;
      int n = n0 + wn + j * 16 + ln;
      #pragma unroll
      for (int i = 0; i < 4; ++i)
        #pragma unroll
        for (int r = 0; r < 4; ++r) {
          int row = row0 + wm + i * 16 + quad * 4 + r;
          qkOut[(long)row * 2048 + n] = f2bf(acc[i][j][r] + bvj);
        }
    }
  } else {
    #pragma unroll
    for (int j = 0; j < 4; ++j) {
      int nl = nloc + wn + j * 16 + ln;
      int hh = nl >> 6, d = nl & 63;
      float bvj = bptr[nl];
      #pragma unroll
      for (int i = 0; i < 4; ++i) {
        int row = row0 + wm + i * 16 + quad * 4;
        int b = row >> 11, t = row & 2047;
        int u = t & 63;   // pi: (kk,n2,quad,r) -> (kk,quad,n2,r); r bits kept
        int pt = (t & ~63) | (u & 0x23) | ((u & 0x10) >> 2) | ((u & 0x0C) << 1);
        short4 sv;
        sv.x = f2bf(acc[i][j][0] + bvj);
        sv.y = f2bf(acc[i][j][1] + bvj);
        sv.z = f2bf(acc[i][j][2] + bvj);
        sv.w = f2bf(acc[i][j][3] + bvj);
        *(short4*)&VT[((long)(b * 16 + hh) * 64 + d) * 2048 + pt] = sv;
      }
    }
  }
}

// ---------------------------------------------------------------------------
// Flash attention, swapped-QK in-register softmax, NO cross-lane traffic.
// mfma(K,Q): lane (ln,quad) holds S[q=i*16+ln][t=nt*16+quad*4+r].
// V stored t-permuted (pi) so the PV A-fragment is built by in-lane packing.
// R10: R7 structure (bias loaded at iter top, consumed same iter — both
// R8/R9 prefetch variants lost a residency level to the extra live range)
// PLUS per-i QK/softmax split to cut peak liveness (sa 32->16, bld dies
// per-half; bfr re-read per i costs 8 ds_read_b128/iter) so the kernel fits
// __launch_bounds__(256,4): 128-reg budget -> 4 blocks/CU (occupancy 23->~50%).
// Spill tripwire: WRITE_SIZE must stay 16MB.
// LDS = K/V double-buffer only (32KB); Ks reused as l-reduce scratch at end.
// ---------------------------------------------------------------------------
__global__ __launch_bounds__(256, 4) void flash_attn(
    const short* __restrict__ qk, const short* __restrict__ VT,
    const _Float16* __restrict__ biasR, short* __restrict__ concat) {
  __shared__ short Ks[2][4096];   // (t, d) xor-swizzled 16B chunks
  __shared__ short Vs[2][4096];   // (d, t-permuted) xor-swizzled 16B chunks
  const int tid = threadIdx.x;
  const int w = tid >> 6, lane = tid & 63, ln = lane & 15, quad = lane >> 4;
  const int q0 = blockIdx.x * 128;
  const int h = blockIdx.y, bb = blockIdx.z;

  // Q fragments (pre-scaled by log2e/8 at prep); B-frag rows q=i*16+ln
  s16x8 qf[2][2];
  const short* qbase = qk + (long)(bb * 2048 + q0 + w * 32) * 2048 + h * 64;
  #pragma unroll
  for (int i = 0; i < 2; ++i)
    #pragma unroll
    for (int kk = 0; kk < 2; ++kk) {
      cvt16 u; u.v = *(const int4*)(qbase + (long)(i * 16 + ln) * 2048 + kk * 32 + quad * 8);
      qf[i][kk] = u.s8;
    }

  f32x4 o[2][4];
  float lsum[2] = {0.f, 0.f};
  #pragma unroll
  for (int i = 0; i < 2; ++i)
    #pragma unroll
    for (int nt = 0; nt < 4; ++nt) o[i][nt] = (f32x4){0.f, 0.f, 0.f, 0.f};

  const short* kbase = qk + (long)bb * 2048 * 2048 + 1024 + h * 64;
  const short* vbase = VT + (long)(bb * 16 + h) * 64 * 2048;
  // bias: per (i,c) 16B at q*2048 + quad*16 + kv*64 + c*8
  const _Float16* bbase = biasR + (long)(q0 + w * 32 + ln) * 2048 + quad * 16;

  // stage kv=0 into buffer 0
  #pragma unroll
  for (int j = 0; j < 2; ++j) {
    int ci = (w * 2 + j) * 64 + lane;
    int r = ci >> 3, cs = (ci & 7) ^ (r & 7);
    __builtin_amdgcn_global_load_lds(GA(kbase + (long)r * 2048 + cs * 8), LA(&Ks[0][(w * 2 + j) * 512]), 16, 0, 0);
    __builtin_amdgcn_global_load_lds(GA(vbase + (long)r * 2048 + cs * 8), LA(&Vs[0][(w * 2 + j) * 512]), 16, 0, 0);
  }

  for (int kv = 0; kv < 32; ++kv) {
    const int t0 = kv * 64, b = kv & 1;
    __syncthreads();  // own DMA drained pre-barrier -> buf b ready, buf b^1 free

    // bias loads for THIS iter (4 x 16B), issued before the prefetch DMAs
    h16x8 bld[2][2];
    #pragma unroll
    for (int i = 0; i < 2; ++i)
      #pragma unroll
      for (int c = 0; c < 2; ++c)
        bld[i][c] = *(const h16x8*)(bbase + (long)i * 16 * 2048 + kv * 64 + c * 8);
    __builtin_amdgcn_sched_barrier(0);

    if (kv < 31) {  // prefetch kv+1 into other buffer
      const short* kb = kbase + (long)(t0 + 64) * 2048;
      const short* vb = vbase + (t0 + 64);
      #pragma unroll
      for (int j = 0; j < 2; ++j) {
        int ci = (w * 2 + j) * 64 + lane;
        int r = ci >> 3, cs = (ci & 7) ^ (r & 7);
        __builtin_amdgcn_global_load_lds(GA(kb + (long)r * 2048 + cs * 8), LA(&Ks[b ^ 1][(w * 2 + j) * 512]), 16, 0, 0);
        __builtin_amdgcn_global_load_lds(GA(vb + (long)r * 2048 + cs * 8), LA(&Vs[b ^ 1][(w * 2 + j) * 512]), 16, 0, 0);
      }
    }

    // per-i QK + softmax (halves sa/bld peak liveness vs processing both i):
    // sa[nt] lane holds S[q=i*16+ln][t=t0+nt*16+quad*4+r]
    s16x8 pa[2][2];
    #pragma unroll
    for (int i = 0; i < 2; ++i) {
      f32x4 sa[4];
      #pragma unroll
      for (int nt = 0; nt < 4; ++nt)
        #pragma unroll
        for (int r = 0; r < 4; ++r)
          sa[nt][r] = fmaf((float)bld[i][nt >> 1][(nt & 1) * 4 + r], LOG2E, -SHIFT);
      #pragma unroll
      for (int kk = 0; kk < 2; ++kk) {
        s16x8 bfr[4];
        #pragma unroll
        for (int nt = 0; nt < 4; ++nt)
          bfr[nt] = *(const s16x8*)&Ks[b][((nt * 16 + ln) << 6) + (((kk * 4 + quad) ^ (ln & 7)) << 3)];
        __builtin_amdgcn_s_setprio(1);
        #pragma unroll
        for (int nt = 0; nt < 4; ++nt)
          sa[nt] = __builtin_amdgcn_mfma_f32_16x16x32_bf16(bfr[nt], qf[i][kk], sa[nt], 0, 0, 0);
        __builtin_amdgcn_s_setprio(0);
      }
      // p = 2^sa; row-sum; pack in-lane into PV A-frags (RNE)
      #pragma unroll
      for (int nt = 0; nt < 4; ++nt)
        #pragma unroll
        for (int r = 0; r < 4; ++r)
          sa[nt][r] = __builtin_amdgcn_exp2f(sa[nt][r]);
      f32x4 vs = (sa[0] + sa[1]) + (sa[2] + sa[3]);
      lsum[i] += (vs[0] + vs[1]) + (vs[2] + vs[3]);
      #pragma unroll
      for (int kk = 0; kk < 2; ++kk) {
        union { unsigned u[4]; s16x8 v; } pw;
        pw.u[0] = pkc(sa[2 * kk][0], sa[2 * kk][1]);
        pw.u[1] = pkc(sa[2 * kk][2], sa[2 * kk][3]);
        pw.u[2] = pkc(sa[2 * kk + 1][0], sa[2 * kk + 1][1]);
        pw.u[3] = pkc(sa[2 * kk + 1][2], sa[2 * kk + 1][3]);
        pa[i][kk] = pw.v;
      }
    }

    // O += P.V   (V t-permuted to match pa's k-slot order)
    #pragma unroll
    for (int kk = 0; kk < 2; ++kk) {
      s16x8 vbf[4];
      #pragma unroll
      for (int nt = 0; nt < 4; ++nt)
        vbf[nt] = *(const s16x8*)&Vs[b][((nt * 16 + ln) << 6) + (((kk * 4 + quad) ^ (ln & 7)) << 3)];
      __builtin_amdgcn_s_setprio(1);
      #pragma unroll
      for (int i = 0; i < 2; ++i)
        #pragma unroll
        for (int nt = 0; nt < 4; ++nt)
          o[i][nt] = __builtin_amdgcn_mfma_f32_16x16x32_bf16(pa[i][kk], vbf[nt], o[i][nt], 0, 0, 0);
      __builtin_amdgcn_s_setprio(0);
    }
  }

  // epilogue: cross-quad l-reduction via LDS (Ks dead; reuse as scratch),
  // then O / l -> concat (rows q = i*16 + quad*4 + r)
  __syncthreads();   // all waves past their last Ks read
  float* lred = (float*)&Ks[0][0];   // 4 waves x 128 floats = 2KB
  #pragma unroll
  for (int i = 0; i < 2; ++i)
    lred[w * 128 + i * 64 + ln * 4 + quad] = lsum[i];
  __syncthreads();
  #pragma unroll
  for (int i = 0; i < 2; ++i) {
    float inv[4];
    #pragma unroll
    for (int r = 0; r < 4; ++r) {
      f32x4 lv = *(const f32x4*)&lred[w * 128 + i * 64 + (quad * 4 + r) * 4];
      inv[r] = __builtin_amdgcn_rcpf((lv[0] + lv[1]) + (lv[2] + lv[3]));
    }
    long rowb = (long)bb * 2048 + q0 + w * 32 + i * 16 + quad * 4;
    #pragma unroll
    for (int nt = 0; nt < 4; ++nt)
      #pragma unroll
      for (int r = 0; r < 4; ++r)
        concat[(rowb + r) * 1024 + h * 64 + nt * 16 + ln] = f2bf(o[i][nt][r] * inv[r]);
  }
}

// ---------------------------------------------------------------------------
// Output GEMM: out[row, n] = sum_k concat[row, k] * WoT[n, k] + bo[n], fp32 out
// ---------------------------------------------------------------------------
__global__ __launch_bounds__(256, 3) void out_gemm(
    const short* __restrict__ A, const short* __restrict__ Bt,
    const float* __restrict__ bo, float* __restrict__ Cout) {
  __shared__ short Asub[128 * 64];
  __shared__ short Bsub[128 * 64];
  const int tid = threadIdx.x;
  const int w = tid >> 6, lane = tid & 63, ln = lane & 15, quad = lane >> 4;
  const int row0 = blockIdx.x * 128, n0 = blockIdx.y * 128;
  const int wm = (w & 1) * 64, wn = (w >> 1) * 64;

  f32x4 acc[4][4];
  #pragma unroll
  for (int i = 0; i < 4; ++i)
    #pragma unroll
    for (int j = 0; j < 4; ++j) acc[i][j] = (f32x4){0.f, 0.f, 0.f, 0.f};

  for (int kt = 0; kt < 16; ++kt) {
    const int k0 = kt * 64;
    #pragma unroll
    for (int j = 0; j < 4; ++j) {
      int ci = (w * 4 + j) * 64 + lane;
      int r = ci >> 3, s = ci & 7, g = s ^ (r & 7);
      const short* ga = A + (long)(row0 + r) * 1024 + k0 + g * 8;
      __builtin_amdgcn_global_load_lds(GA(ga), LA(&Asub[ci * 8]), 16, 0, 0);
      const short* gb = Bt + (long)(n0 + r) * 1024 + k0 + g * 8;
      __builtin_amdgcn_global_load_lds(GA(gb), LA(&Bsub[ci * 8]), 16, 0, 0);
    }
    __syncthreads();
    #pragma unroll
    for (int kk = 0; kk < 2; ++kk) {
      s16x8 af[4], bfr[4];
      #pragma unroll
      for (int i = 0; i < 4; ++i) {
        int ra = wm + i * 16 + ln;
        int slot = (kk * 4 + quad) ^ (ra & 7);
        af[i] = *(const s16x8*)&Asub[ra * 64 + slot * 8];
      }
      #pragma unroll
      for (int j = 0; j < 4; ++j) {
        int rb = wn + j * 16 + ln;
        int slot = (kk * 4 + quad) ^ (rb & 7);
        bfr[j] = *(const s16x8*)&Bsub[rb * 64 + slot * 8];
      }
      #pragma unroll
      for (int i = 0; i < 4; ++i)
        #pragma unroll
        for (int j = 0; j < 4; ++j)
          acc[i][j] = __builtin_amdgcn_mfma_f32_16x16x32_bf16(af[i], bfr[j], acc[i][j], 0, 0, 0);
    }
    __syncthreads();
  }
  #pragma unroll
  for (int j = 0; j < 4; ++j) {
    int n = n0 + wn + j * 16 + ln;
    float bvj = bo[n];
    #pragma unroll
    for (int i = 0; i < 4; ++i)
      #pragma unroll
      for (int r = 0; r < 4; ++r) {
        int row = row0 + wm + i * 16 + quad * 4 + r;
        Cout[(long)row * 1024 + n] = acc[i][j][r] + bvj;
      }
  }
}

// ---------------------------------------------------------------------------
// ws layout (72 MB total, proven budget):
//   [ 0, 8M)  WqkvT bf16 (6MB) -> overwritten by biasR fp16 (8MB) after proj
//   [ 8,40M)  qk bf16 (8192 x 2048)
//   [40,56M)  VT bf16 [(b,h,d) x pi(t)] -> WoT bf16 (2MB) overwrites after flash
//   [56,72M)  concat bf16 (8192 x 1024)
// ---------------------------------------------------------------------------
extern "C" void kernel_launch(void* const* d_in, const int* in_sizes, int n_in,
                              void* d_out, int out_size, void* d_ws, size_t ws_size,
                              hipStream_t stream) {
  const float* query = (const float*)d_in[0];
  const float* key_  = (const float*)d_in[1];
  const float* value = (const float*)d_in[2];
  const float* abias = (const float*)d_in[3];
  const float* Wq = (const float*)d_in[4];
  const float* bq = (const float*)d_in[5];
  const float* Wk = (const float*)d_in[6];
  const float* bk = (const float*)d_in[7];
  const float* Wv = (const float*)d_in[8];
  const float* bv = (const float*)d_in[9];
  const float* Wo = (const float*)d_in[10];
  const float* bo = (const float*)d_in[11];
  float* out = (float*)d_out;

  char* ws = (char*)d_ws;
  short*    WqkvT  = (short*)(ws);
  _Float16* biasR  = (_Float16*)(ws);
  short*    qk     = (short*)(ws + 8388608);
  short*    VT     = (short*)(ws + 41943040);
  short*    WoT    = (short*)(ws + 41943040);
  short*    concat = (short*)(ws + 58720256);

  dim3 tb(32, 8);
  transpose_cast<<<dim3(2, 32, 16), tb, 0, stream>>>(Wq, WqkvT,           1024, 64, 65536L, 65536L, SCALE_Q);
  transpose_cast<<<dim3(2, 32, 16), tb, 0, stream>>>(Wk, WqkvT + 1048576, 1024, 64, 65536L, 65536L, 1.0f);
  transpose_cast<<<dim3(2, 32, 16), tb, 0, stream>>>(Wv, WqkvT + 2097152, 1024, 64, 65536L, 65536L, 1.0f);
  proj_gemm<<<dim3(64, 24), 256, 0, stream>>>(query, key_, value, WqkvT, bq, bk, bv, qk, VT);
  bias_rearrange<<<dim3(2048), 256, 0, stream>>>(abias, biasR);
  flash_attn<<<dim3(16, 16, 4), 256, 0, stream>>>(qk, VT, biasR, concat);
  transpose_cast<<<dim3(32, 32, 1), tb, 0, stream>>>(Wo, WoT, 1024, 1024, 0L, 0L, 1.0f);
  out_gemm<<<dim3(64, 8), 256, 0, stream>>>(concat, WoT, bo, out);
}

// Round 11
// 364.019 us; speedup vs baseline: 1.0511x; 1.0145x over previous
//
#include <hip/hip_runtime.h>

#define S_LEN 2048
#define E_DIM 1024
#define H_NUM 16

typedef __attribute__((ext_vector_type(8))) short s16x8;
typedef __attribute__((ext_vector_type(4))) float f32x4;
typedef __attribute__((ext_vector_type(4))) _Float16 h16x4;
typedef __attribute__((ext_vector_type(8))) _Float16 h16x8;

#define GA(p) ((__attribute__((address_space(1))) void*)(p))
#define LA(p) ((__attribute__((address_space(3))) void*)(p))

#define LOG2E 1.4426950408889634f
#define SCALE_Q (0.125f * LOG2E)
#define SHIFT 12.0f   // folded into QK accumulator init; cancels in p/l

union cvt16 { int4 v; s16x8 s8; short e[8]; };

__device__ __forceinline__ short f2bf(float f) {  // RNE
  union { float f; unsigned u; } v; v.f = f;
  unsigned r = v.u + 0x7FFFu + ((v.u >> 16) & 1u);
  return (short)(r >> 16);
}
__device__ __forceinline__ unsigned pkc(float lo, float hi) {  // 2xbf16, RNE
  unsigned r;
  asm("v_cvt_pk_bf16_f32 %0, %1, %2" : "=v"(r) : "v"(lo), "v"(hi));
  return r;
}

// ---------------------------------------------------------------------------
// Transpose + cast + scale: src fp32 (R x C) -> dst bf16 (C x R), batched.
// ---------------------------------------------------------------------------
__global__ void transpose_cast(const float* __restrict__ src, short* __restrict__ dst,
                               int R, int C, long sbs, long dbs, float scale) {
  __shared__ float tile[32][33];
  const float* s = src + (long)blockIdx.z * sbs;
  short* d = dst + (long)blockIdx.z * dbs;
  int c0 = blockIdx.x * 32, r0 = blockIdx.y * 32;
  #pragma unroll
  for (int i = threadIdx.y; i < 32; i += 8)
    tile[i][threadIdx.x] = s[(long)(r0 + i) * C + c0 + threadIdx.x];
  __syncthreads();
  #pragma unroll
  for (int i = threadIdx.y; i < 32; i += 8)
    d[(long)(c0 + i) * R + r0 + threadIdx.x] = f2bf(tile[threadIdx.x][i] * scale);
}

// ---------------------------------------------------------------------------
// Bias rearrange for swapped-QK flash layout. Lane (ln,quad) of q-row
// q = q0+w*32+i*16+ln needs, per kv tile, bias[q][kv*64 + nt*16 + quad*4 + r].
// Pack per (q, kv, quad) 16 f16 values:
//   biasR[q*2048 + kv*64 + quad*16 + c*8 + n2*4 + r] = bias[q][kv*64+(2c+n2)*16+quad*4+r]
// so flash does 2 x 16B loads per (i) per iter.
// ---------------------------------------------------------------------------
__global__ void bias_rearrange(const float* __restrict__ bias, _Float16* __restrict__ biasR) {
  long g = (long)blockIdx.x * 256 + threadIdx.x;   // 16B-chunk id, 524288 total
  int q    = (int)(g >> 8);
  int kv   = ((int)(g >> 3)) & 31;
  int quad = ((int)(g >> 1)) & 3;
  int c    = (int)g & 1;
  const float* src = bias + (long)q * 2048 + kv * 64 + c * 32 + quad * 4;
  f32x4 lo = *(const f32x4*)(src);        // n2 = 0 : t = base + r
  f32x4 hi = *(const f32x4*)(src + 16);   // n2 = 1 : t = base + 16 + r
  h16x8 hv;
  #pragma unroll
  for (int e = 0; e < 4; ++e) { hv[e] = (_Float16)lo[e]; hv[4 + e] = (_Float16)hi[e]; }
  *(h16x8*)(biasR + g * 8) = hv;
}

// ---------------------------------------------------------------------------
// QKV projection GEMM, fp32-A direct DMA staging.
// A: fp32 (8192x1024) per segment, Bt: bf16 (3072x1024).
// Segs 0/1 -> qk (8192x2048); seg 2 -> VT [(b*16+h)*64+d][pi(t)] where pi
// permutes t within each 64-block (bit shuffle (kk,n2,quad,r)->(kk,quad,n2,r))
// so flash's in-lane P packing lines up with V's PV k-slots.
// A-fragment bf16 conversion via v_cvt_pk_bf16_f32 (4 instrs/frag, RNE).
// ---------------------------------------------------------------------------
__global__ __launch_bounds__(256, 3) void proj_gemm(
    const float* __restrict__ Aq, const float* __restrict__ Ak, const float* __restrict__ Av,
    const short* __restrict__ Bt,
    const float* __restrict__ bq, const float* __restrict__ bk, const float* __restrict__ bv,
    short* __restrict__ qkOut, short* __restrict__ VT) {
  __shared__ float Asub[128 * 64];   // 32 KB, fp32, swizzled 16B chunks
  __shared__ short Bsub[128 * 64];   // 16 KB, bf16, swizzled 16B chunks
  const int tid = threadIdx.x;
  const int w = tid >> 6, lane = tid & 63, ln = lane & 15, quad = lane >> 4;
  const int row0 = blockIdx.x * 128, n0 = blockIdx.y * 128;
  const int seg = n0 >> 10;
  const float* A = (seg == 0) ? Aq : ((seg == 1) ? Ak : Av);
  const float* bptr = (seg == 0) ? bq : ((seg == 1) ? bk : bv);
  const float bscale = (seg == 0) ? SCALE_Q : 1.0f;
  const int nloc = n0 & 1023;
  const int wm = (w & 1) * 64, wn = (w >> 1) * 64;

  f32x4 acc[4][4];
  #pragma unroll
  for (int i = 0; i < 4; ++i)
    #pragma unroll
    for (int j = 0; j < 4; ++j) acc[i][j] = (f32x4){0.f, 0.f, 0.f, 0.f};

  for (int kt = 0; kt < 16; ++kt) {
    const int k0 = kt * 64;
    #pragma unroll
    for (int j = 0; j < 4; ++j) {
      int ci = (w * 4 + j) * 64 + lane;
      int r = ci >> 3, s = ci & 7, g = s ^ (r & 7);
      const short* gb = Bt + (long)(n0 + r) * 1024 + k0 + g * 8;
      __builtin_amdgcn_global_load_lds(GA(gb), LA(&Bsub[ci * 8]), 16, 0, 0);
    }
    #pragma unroll
    for (int it = 0; it < 8; ++it) {
      int ci = it * 256 + tid;
      int r = ci >> 4, s = ci & 15, g = (s & 8) | ((s & 7) ^ (r & 7));
      const float* ga = A + (long)(row0 + r) * 1024 + k0 + g * 4;
      __builtin_amdgcn_global_load_lds(GA(ga), LA(&Asub[ci * 4]), 16, 0, 0);
    }
    __syncthreads();
    #pragma unroll
    for (int kk = 0; kk < 2; ++kk) {
      s16x8 af[4], bfr[4];
      #pragma unroll
      for (int i = 0; i < 4; ++i) {
        int ra = wm + i * 16 + ln;
        int c0 = kk * 8 + quad * 2;
        int s0 = (c0 & 8) | ((c0 & 7) ^ (ra & 7));
        int c1 = c0 + 1;
        int s1 = (c1 & 8) | ((c1 & 7) ^ (ra & 7));
        f32x4 lo = *(const f32x4*)&Asub[ra * 64 + s0 * 4];
        f32x4 hi = *(const f32x4*)&Asub[ra * 64 + s1 * 4];
        union { unsigned u[4]; s16x8 v; } t;
        t.u[0] = pkc(lo[0], lo[1]);
        t.u[1] = pkc(lo[2], lo[3]);
        t.u[2] = pkc(hi[0], hi[1]);
        t.u[3] = pkc(hi[2], hi[3]);
        af[i] = t.v;
      }
      #pragma unroll
      for (int j = 0; j < 4; ++j) {
        int rb = wn + j * 16 + ln;
        int slot = (kk * 4 + quad) ^ (rb & 7);
        bfr[j] = *(const s16x8*)&Bsub[rb * 64 + slot * 8];
      }
      #pragma unroll
      for (int i = 0; i < 4; ++i)
        #pragma unroll
        for (int j = 0; j < 4; ++j)
          acc[i][j] = __builtin_amdgcn_mfma_f32_16x16x32_bf16(af[i], bfr[j], acc[i][j], 0, 0, 0);
    }
    __syncthreads();
  }
  if (seg < 2) {
    #pragma unroll
    for (int j = 0; j < 4; ++j) {
      float bvj = bptr[nloc + wn + j * 16 + ln] * bscale;
      int n = n0 + wn + j * 16 + ln;
      #pragma unroll
      for (int i = 0; i < 4; ++i)
        #pragma unroll
        for (int r = 0; r < 4; ++r) {
          int row = row0 + wm + i * 16 + quad * 4 + r;
          qkOut[(long)row * 2048 + n] = f2bf(acc[i][j][r] + bvj);
        }
    }
  } else {
    #pragma unroll
    for (int j = 0; j < 4; ++j) {
      int nl = nloc + wn + j * 16 + ln;
      int hh = nl >> 6, d = nl & 63;
      float bvj = bptr[nl];
      #pragma unroll
      for (int i = 0; i < 4; ++i) {
        int row = row0 + wm + i * 16 + quad * 4;
        int b = row >> 11, t = row & 2047;
        int u = t & 63;   // pi: (kk,n2,quad,r) -> (kk,quad,n2,r); r bits kept
        int pt = (t & ~63) | (u & 0x23) | ((u & 0x10) >> 2) | ((u & 0x0C) << 1);
        short4 sv;
        sv.x = f2bf(acc[i][j][0] + bvj);
        sv.y = f2bf(acc[i][j][1] + bvj);
        sv.z = f2bf(acc[i][j][2] + bvj);
        sv.w = f2bf(acc[i][j][3] + bvj);
        *(short4*)&VT[((long)(b * 16 + hh) * 64 + d) * 2048 + pt] = sv;
      }
    }
  }
}

// ---------------------------------------------------------------------------
// Flash attention, swapped-QK in-register softmax, NO cross-lane traffic.
// mfma(K,Q): lane (ln,quad) holds S[q=i*16+ln][t=nt*16+quad*4+r].
// V stored t-permuted (pi) so the PV A-fragment is built by in-lane packing.
// R11 geometry fix: R7-R10 all had grid = 4 blocks/CU with only ~3 resident
// -> permanent 1/4-of-time tail at 1/3 occupancy (measured 33-35% flat).
// Now 512-thread blocks (8 waves, each wave still owns 32 q-rows), q-tile
// 256 rows, grid (8,16,4) = 512 blocks = EXACTLY 2/CU, both resident under
// __launch_bounds__(512,4) (128-reg cap, same as R10's proven fit):
// 16 waves/CU steady-state, zero tail. Staging halves per wave (1 DMA
// pair/iter). Per-i QK/softmax split kept (peak liveness < 128).
// Spill tripwire: WRITE_SIZE ~16-20MB.
// LDS = K/V double-buffer only (32KB); Ks reused as l-reduce scratch at end.
// ---------------------------------------------------------------------------
__global__ __launch_bounds__(512, 4) void flash_attn(
    const short* __restrict__ qk, const short* __restrict__ VT,
    const _Float16* __restrict__ biasR, short* __restrict__ concat) {
  __shared__ short Ks[2][4096];   // (t, d) xor-swizzled 16B chunks
  __shared__ short Vs[2][4096];   // (d, t-permuted) xor-swizzled 16B chunks
  const int tid = threadIdx.x;
  const int w = tid >> 6, lane = tid & 63, ln = lane & 15, quad = lane >> 4;
  const int q0 = blockIdx.x * 256;
  const int h = blockIdx.y, bb = blockIdx.z;

  // Q fragments (pre-scaled by log2e/8 at prep); B-frag rows q=i*16+ln
  s16x8 qf[2][2];
  const short* qbase = qk + (long)(bb * 2048 + q0 + w * 32) * 2048 + h * 64;
  #pragma unroll
  for (int i = 0; i < 2; ++i)
    #pragma unroll
    for (int kk = 0; kk < 2; ++kk) {
      cvt16 u; u.v = *(const int4*)(qbase + (long)(i * 16 + ln) * 2048 + kk * 32 + quad * 8);
      qf[i][kk] = u.s8;
    }

  f32x4 o[2][4];
  float lsum[2] = {0.f, 0.f};
  #pragma unroll
  for (int i = 0; i < 2; ++i)
    #pragma unroll
    for (int nt = 0; nt < 4; ++nt) o[i][nt] = (f32x4){0.f, 0.f, 0.f, 0.f};

  const short* kbase = qk + (long)bb * 2048 * 2048 + 1024 + h * 64;
  const short* vbase = VT + (long)(bb * 16 + h) * 64 * 2048;
  // bias: per (i,c) 16B at q*2048 + quad*16 + kv*64 + c*8
  const _Float16* bbase = biasR + (long)(q0 + w * 32 + ln) * 2048 + quad * 16;

  // stage kv=0 into buffer 0 (8 waves cover the 512 16B chunks: 1 pair/wave)
  {
    int ci = w * 64 + lane;
    int r = ci >> 3, cs = (ci & 7) ^ (r & 7);
    __builtin_amdgcn_global_load_lds(GA(kbase + (long)r * 2048 + cs * 8), LA(&Ks[0][w * 512]), 16, 0, 0);
    __builtin_amdgcn_global_load_lds(GA(vbase + (long)r * 2048 + cs * 8), LA(&Vs[0][w * 512]), 16, 0, 0);
  }

  for (int kv = 0; kv < 32; ++kv) {
    const int t0 = kv * 64, b = kv & 1;
    __syncthreads();  // own DMA drained pre-barrier -> buf b ready, buf b^1 free

    // bias loads for THIS iter (4 x 16B), issued before the prefetch DMAs
    h16x8 bld[2][2];
    #pragma unroll
    for (int i = 0; i < 2; ++i)
      #pragma unroll
      for (int c = 0; c < 2; ++c)
        bld[i][c] = *(const h16x8*)(bbase + (long)i * 16 * 2048 + kv * 64 + c * 8);
    __builtin_amdgcn_sched_barrier(0);

    if (kv < 31) {  // prefetch kv+1 into other buffer
      const short* kb = kbase + (long)(t0 + 64) * 2048;
      const short* vb = vbase + (t0 + 64);
      int ci = w * 64 + lane;
      int r = ci >> 3, cs = (ci & 7) ^ (r & 7);
      __builtin_amdgcn_global_load_lds(GA(kb + (long)r * 2048 + cs * 8), LA(&Ks[b ^ 1][w * 512]), 16, 0, 0);
      __builtin_amdgcn_global_load_lds(GA(vb + (long)r * 2048 + cs * 8), LA(&Vs[b ^ 1][w * 512]), 16, 0, 0);
    }

    // per-i QK + softmax (halves sa/bld peak liveness vs processing both i):
    // sa[nt] lane holds S[q=i*16+ln][t=t0+nt*16+quad*4+r]
    s16x8 pa[2][2];
    #pragma unroll
    for (int i = 0; i < 2; ++i) {
      f32x4 sa[4];
      #pragma unroll
      for (int nt = 0; nt < 4; ++nt)
        #pragma unroll
        for (int r = 0; r < 4; ++r)
          sa[nt][r] = fmaf((float)bld[i][nt >> 1][(nt & 1) * 4 + r], LOG2E, -SHIFT);
      #pragma unroll
      for (int kk = 0; kk < 2; ++kk) {
        s16x8 bfr[4];
        #pragma unroll
        for (int nt = 0; nt < 4; ++nt)
          bfr[nt] = *(const s16x8*)&Ks[b][((nt * 16 + ln) << 6) + (((kk * 4 + quad) ^ (ln & 7)) << 3)];
        __builtin_amdgcn_s_setprio(1);
        #pragma unroll
        for (int nt = 0; nt < 4; ++nt)
          sa[nt] = __builtin_amdgcn_mfma_f32_16x16x32_bf16(bfr[nt], qf[i][kk], sa[nt], 0, 0, 0);
        __builtin_amdgcn_s_setprio(0);
      }
      // p = 2^sa; row-sum; pack in-lane into PV A-frags (RNE)
      #pragma unroll
      for (int nt = 0; nt < 4; ++nt)
        #pragma unroll
        for (int r = 0; r < 4; ++r)
          sa[nt][r] = __builtin_amdgcn_exp2f(sa[nt][r]);
      f32x4 vs = (sa[0] + sa[1]) + (sa[2] + sa[3]);
      lsum[i] += (vs[0] + vs[1]) + (vs[2] + vs[3]);
      #pragma unroll
      for (int kk = 0; kk < 2; ++kk) {
        union { unsigned u[4]; s16x8 v; } pw;
        pw.u[0] = pkc(sa[2 * kk][0], sa[2 * kk][1]);
        pw.u[1] = pkc(sa[2 * kk][2], sa[2 * kk][3]);
        pw.u[2] = pkc(sa[2 * kk + 1][0], sa[2 * kk + 1][1]);
        pw.u[3] = pkc(sa[2 * kk + 1][2], sa[2 * kk + 1][3]);
        pa[i][kk] = pw.v;
      }
    }

    // O += P.V   (V t-permuted to match pa's k-slot order)
    #pragma unroll
    for (int kk = 0; kk < 2; ++kk) {
      s16x8 vbf[4];
      #pragma unroll
      for (int nt = 0; nt < 4; ++nt)
        vbf[nt] = *(const s16x8*)&Vs[b][((nt * 16 + ln) << 6) + (((kk * 4 + quad) ^ (ln & 7)) << 3)];
      __builtin_amdgcn_s_setprio(1);
      #pragma unroll
      for (int i = 0; i < 2; ++i)
        #pragma unroll
        for (int nt = 0; nt < 4; ++nt)
          o[i][nt] = __builtin_amdgcn_mfma_f32_16x16x32_bf16(pa[i][kk], vbf[nt], o[i][nt], 0, 0, 0);
      __builtin_amdgcn_s_setprio(0);
    }
  }

  // epilogue: cross-quad l-reduction via LDS (Ks dead; reuse as scratch),
  // then O / l -> concat (rows q = i*16 + quad*4 + r)
  __syncthreads();   // all waves past their last Ks read
  float* lred = (float*)&Ks[0][0];   // 8 waves x 128 floats = 4KB
  #pragma unroll
  for (int i = 0; i < 2; ++i)
    lred[w * 128 + i * 64 + ln * 4 + quad] = lsum[i];
  __syncthreads();
  #pragma unroll
  for (int i = 0; i < 2; ++i) {
    float inv[4];
    #pragma unroll
    for (int r = 0; r < 4; ++r) {
      f32x4 lv = *(const f32x4*)&lred[w * 128 + i * 64 + (quad * 4 + r) * 4];
      inv[r] = __builtin_amdgcn_rcpf((lv[0] + lv[1]) + (lv[2] + lv[3]));
    }
    long rowb = (long)bb * 2048 + q0 + w * 32 + i * 16 + quad * 4;
    #pragma unroll
    for (int nt = 0; nt < 4; ++nt)
      #pragma unroll
      for (int r = 0; r < 4; ++r)
        concat[(rowb + r) * 1024 + h * 64 + nt * 16 + ln] = f2bf(o[i][nt][r] * inv[r]);
  }
}

// ---------------------------------------------------------------------------
// Output GEMM: out[row, n] = sum_k concat[row, k] * WoT[n, k] + bo[n], fp32 out
// ---------------------------------------------------------------------------
__global__ __launch_bounds__(256, 3) void out_gemm(
    const short* __restrict__ A, const short* __restrict__ Bt,
    const float* __restrict__ bo, float* __restrict__ Cout) {
  __shared__ short Asub[128 * 64];
  __shared__ short Bsub[128 * 64];
  const int tid = threadIdx.x;
  const int w = tid >> 6, lane = tid & 63, ln = lane & 15, quad = lane >> 4;
  const int row0 = blockIdx.x * 128, n0 = blockIdx.y * 128;
  const int wm = (w & 1) * 64, wn = (w >> 1) * 64;

  f32x4 acc[4][4];
  #pragma unroll
  for (int i = 0; i < 4; ++i)
    #pragma unroll
    for (int j = 0; j < 4; ++j) acc[i][j] = (f32x4){0.f, 0.f, 0.f, 0.f};

  for (int kt = 0; kt < 16; ++kt) {
    const int k0 = kt * 64;
    #pragma unroll
    for (int j = 0; j < 4; ++j) {
      int ci = (w * 4 + j) * 64 + lane;
      int r = ci >> 3, s = ci & 7, g = s ^ (r & 7);
      const short* ga = A + (long)(row0 + r) * 1024 + k0 + g * 8;
      __builtin_amdgcn_global_load_lds(GA(ga), LA(&Asub[ci * 8]), 16, 0, 0);
      const short* gb = Bt + (long)(n0 + r) * 1024 + k0 + g * 8;
      __builtin_amdgcn_global_load_lds(GA(gb), LA(&Bsub[ci * 8]), 16, 0, 0);
    }
    __syncthreads();
    #pragma unroll
    for (int kk = 0; kk < 2; ++kk) {
      s16x8 af[4], bfr[4];
      #pragma unroll
      for (int i = 0; i < 4; ++i) {
        int ra = wm + i * 16 + ln;
        int slot = (kk * 4 + quad) ^ (ra & 7);
        af[i] = *(const s16x8*)&Asub[ra * 64 + slot * 8];
      }
      #pragma unroll
      for (int j = 0; j < 4; ++j) {
        int rb = wn + j * 16 + ln;
        int slot = (kk * 4 + quad) ^ (rb & 7);
        bfr[j] = *(const s16x8*)&Bsub[rb * 64 + slot * 8];
      }
      #pragma unroll
      for (int i = 0; i < 4; ++i)
        #pragma unroll
        for (int j = 0; j < 4; ++j)
          acc[i][j] = __builtin_amdgcn_mfma_f32_16x16x32_bf16(af[i], bfr[j], acc[i][j], 0, 0, 0);
    }
    __syncthreads();
  }
  #pragma unroll
  for (int j = 0; j < 4; ++j) {
    int n = n0 + wn + j * 16 + ln;
    float bvj = bo[n];
    #pragma unroll
    for (int i = 0; i < 4; ++i)
      #pragma unroll
      for (int r = 0; r < 4; ++r) {
        int row = row0 + wm + i * 16 + quad * 4 + r;
        Cout[(long)row * 1024 + n] = acc[i][j][r] + bvj;
      }
  }
}

// ---------------------------------------------------------------------------
// ws layout (72 MB total, proven budget):
//   [ 0, 8M)  WqkvT bf16 (6MB) -> overwritten by biasR fp16 (8MB) after proj
//   [ 8,40M)  qk bf16 (8192 x 2048)
//   [40,56M)  VT bf16 [(b,h,d) x pi(t)] -> WoT bf16 (2MB) overwrites after flash
//   [56,72M)  concat bf16 (8192 x 1024)
// ---------------------------------------------------------------------------
extern "C" void kernel_launch(void* const* d_in, const int* in_sizes, int n_in,
                              void* d_out, int out_size, void* d_ws, size_t ws_size,
                              hipStream_t stream) {
  const float* query = (const float*)d_in[0];
  const float* key_  = (const float*)d_in[1];
  const float* value = (const float*)d_in[2];
  const float* abias = (const float*)d_in[3];
  const float* Wq = (const float*)d_in[4];
  const float* bq = (const float*)d_in[5];
  const float* Wk = (const float*)d_in[6];
  const float* bk = (const float*)d_in[7];
  const float* Wv = (const float*)d_in[8];
  const float* bv = (const float*)d_in[9];
  const float* Wo = (const float*)d_in[10];
  const float* bo = (const float*)d_in[11];
  float* out = (float*)d_out;

  char* ws = (char*)d_ws;
  short*    WqkvT  = (short*)(ws);
  _Float16* biasR  = (_Float16*)(ws);
  short*    qk     = (short*)(ws + 8388608);
  short*    VT     = (short*)(ws + 41943040);
  short*    WoT    = (short*)(ws + 41943040);
  short*    concat = (short*)(ws + 58720256);

  dim3 tb(32, 8);
  transpose_cast<<<dim3(2, 32, 16), tb, 0, stream>>>(Wq, WqkvT,           1024, 64, 65536L, 65536L, SCALE_Q);
  transpose_cast<<<dim3(2, 32, 16), tb, 0, stream>>>(Wk, WqkvT + 1048576, 1024, 64, 65536L, 65536L, 1.0f);
  transpose_cast<<<dim3(2, 32, 16), tb, 0, stream>>>(Wv, WqkvT + 2097152, 1024, 64, 65536L, 65536L, 1.0f);
  proj_gemm<<<dim3(64, 24), 256, 0, stream>>>(query, key_, value, WqkvT, bq, bk, bv, qk, VT);
  bias_rearrange<<<dim3(2048), 256, 0, stream>>>(abias, biasR);
  flash_attn<<<dim3(8, 16, 4), 512, 0, stream>>>(qk, VT, biasR, concat);
  transpose_cast<<<dim3(32, 32, 1), tb, 0, stream>>>(Wo, WoT, 1024, 1024, 0L, 0L, 1.0f);
  out_gemm<<<dim3(64, 8), 256, 0, stream>>>(concat, WoT, bo, out);
}